// Round 3
// baseline (433.983 us; speedup 1.0000x reference)
//
#include <hip/hip_runtime.h>

#define NPG 50
#define EPG 400
#define NGRAPH 32768
#define NNODE (NGRAPH * NPG)
#define NEDGE (NGRAPH * EPG)
#define BN_EPS 1e-5f

// ---- workspace layout (float offsets) ----
#define WS_A1 0            // [800]  A1[50][16]
#define WS_A2 800          // [800]  A2[50][16]
#define WS_K0 1600         // [16]   const + fc1_b
#define WS_ST1 1616        // [32]   sum[16], sumsq[16] for BN1
#define WS_W2 1648         // [512]  folded fc2 weights [16][32]
#define WS_B2 2160         // [32]   folded fc2 bias
#define WS_ST2 2192        // [64]   sum[32], sumsq[32] for BN2
#define WS_W3 2256         // [64]   folded fc3 weights [32][2]
#define WS_B3 2320         // [2]    folded fc3 bias
#define WS_H1 4096         // [NGRAPH*16] fp32  (total ws ~= 2.11 MB)

// kept so any build step looking for the stub symbol still finds it
__global__ void FullGCN_52286931861996_kernel() {}

struct Params12 { const float* p[12]; };

// ---------------- K0: precompute A1/A2/K0vec, zero BN accumulators ----------------
__global__ void k0_pre(Params12 wp, const float* __restrict__ fc1w,
                       const float* __restrict__ fc1b, float* __restrict__ ws) {
    __shared__ float U[12], C[12], Bc[12];
    int tid = threadIdx.x;
    if (tid < 12) {
        int b = tid >> 2, j = tid & 3;
        const float* W1 = wp.p[b * 4 + 0];   // [1,4]
        const float* b1 = wp.p[b * 4 + 1];   // [4]
        const float* W2 = wp.p[b * 4 + 2];   // [4,4]
        const float* b2 = wp.p[b * 4 + 3];   // [4]
        float u = 0.f, c = 0.f;
        for (int k = 0; k < 4; k++) {
            float w2 = W2[k * 4 + j];
            u += W1[k] * w2;
            c += b1[k] * w2;
        }
        U[tid] = u; C[tid] = c; Bc[tid] = b2[j];
    }
    __syncthreads();
    // A1[n][o] = sum_f U[f]*fc1w[(n*12+f)*16+o] ; A2 with C
    for (int idx = tid; idx < 1600; idx += blockDim.x) {
        int which = (idx >= 800);
        int e = which ? idx - 800 : idx;
        int n = e >> 4, o = e & 15;
        const float* V = which ? C : U;
        float a = 0.f;
        for (int f = 0; f < 12; f++) a += V[f] * fc1w[(n * 12 + f) * 16 + o];
        ws[idx] = a;
    }
    if (tid < 16) {
        float a = fc1b[tid];
        for (int n = 0; n < NPG; n++)
            for (int f = 0; f < 12; f++)
                a += Bc[f] * fc1w[(n * 12 + f) * 16 + tid];
        ws[WS_K0 + tid] = a;
    }
    if (tid < 32) ws[WS_ST1 + tid] = 0.f;
    if (tid >= 64 && tid < 128) ws[WS_ST2 + (tid - 64)] = 0.f;
}

// ---------------- K1: per-graph GCN (one wave per graph) + fc1 fold + relu ----------------
#define GPB 4
__global__ __launch_bounds__(256) void k1_gcn(const float* __restrict__ x,
                                              const int* __restrict__ edges,
                                              const float* __restrict__ ws,
                                              float* __restrict__ h1) {
    __shared__ float sA[1616];  // A1 | A2 | K0vec
    __shared__ float sX[GPB][NPG];
    __shared__ float sDinv[GPB][NPG];
    __shared__ int sDeg[GPB][NPG];
    __shared__ float sPx[GPB][NPG];
    __shared__ float sR[GPB][NPG];
    __shared__ float sPpx[GPB][NPG];

    int tid = threadIdx.x;
    for (int i = tid; i < 1616; i += 256) sA[i] = ws[i];

    int w = tid >> 6, lane = tid & 63;
    int g = blockIdx.x * GPB + w;
    int nb = g * NPG;

    if (lane < NPG) {
        sDeg[w][lane] = 1;  // self-loop
        sX[w][lane] = x[nb + lane];
    }

    // this graph's 400 edges: edge_index row 0 = src (E ints), row 1 = dst
    const int4* s4 = (const int4*)edges;
    const int4* d4 = s4 + (NEDGE / 4);
    int base = g * (EPG / 4);
    int4 sa = s4[base + lane];
    int4 da = d4[base + lane];
    bool m2 = (64 + lane) < (EPG / 4);
    int4 sb = make_int4(0, 0, 0, 0), db = make_int4(0, 0, 0, 0);
    if (m2) { sb = s4[base + 64 + lane]; db = d4[base + 64 + lane]; }

    int sl[8], dl[8];
    sl[0] = sa.x - nb; sl[1] = sa.y - nb; sl[2] = sa.z - nb; sl[3] = sa.w - nb;
    dl[0] = da.x - nb; dl[1] = da.y - nb; dl[2] = da.z - nb; dl[3] = da.w - nb;
    sl[4] = sb.x - nb; sl[5] = sb.y - nb; sl[6] = sb.z - nb; sl[7] = sb.w - nb;
    dl[4] = db.x - nb; dl[5] = db.y - nb; dl[6] = db.z - nb; dl[7] = db.w - nb;

    __syncthreads();
    #pragma unroll
    for (int e = 0; e < 4; e++) atomicAdd(&sDeg[w][dl[e]], 1);
    if (m2) {
        #pragma unroll
        for (int e = 4; e < 8; e++) atomicAdd(&sDeg[w][dl[e]], 1);
    }
    __syncthreads();
    if (lane < NPG) {
        float dv = rsqrtf((float)sDeg[w][lane]);
        sDinv[w][lane] = dv;
        float d2 = dv * dv;
        sPx[w][lane] = d2 * sX[w][lane];  // self-loop contribution
        sR[w][lane] = d2;
    }
    __syncthreads();
    // pass 1: px = P@x, r = P@1
    float wn[8];
    #pragma unroll
    for (int e = 0; e < 4; e++) {
        wn[e] = sDinv[w][sl[e]] * sDinv[w][dl[e]];
        atomicAdd(&sPx[w][dl[e]], wn[e] * sX[w][sl[e]]);
        atomicAdd(&sR[w][dl[e]], wn[e]);
    }
    if (m2) {
        #pragma unroll
        for (int e = 4; e < 8; e++) {
            wn[e] = sDinv[w][sl[e]] * sDinv[w][dl[e]];
            atomicAdd(&sPx[w][dl[e]], wn[e] * sX[w][sl[e]]);
            atomicAdd(&sR[w][dl[e]], wn[e]);
        }
    }
    __syncthreads();
    if (lane < NPG) {
        float dv = sDinv[w][lane];
        sPpx[w][lane] = dv * dv * sPx[w][lane];
    }
    __syncthreads();
    // pass 2: ppx = P@px
    #pragma unroll
    for (int e = 0; e < 4; e++) atomicAdd(&sPpx[w][dl[e]], wn[e] * sPx[w][sl[e]]);
    if (m2) {
        #pragma unroll
        for (int e = 4; e < 8; e++) atomicAdd(&sPpx[w][dl[e]], wn[e] * sPx[w][sl[e]]);
    }
    __syncthreads();
    // z1[o] = sum_n ppx[n]*A1[n][o] + r[n]*A2[n][o] + K0[o]; relu; store
    int o = lane >> 2, q = lane & 3;
    float acc = 0.f;
    for (int n = q; n < NPG; n += 4)
        acc += sPpx[w][n] * sA[n * 16 + o] + sR[w][n] * sA[800 + n * 16 + o];
    acc += __shfl_down(acc, 2, 4);
    acc += __shfl_down(acc, 1, 4);
    if (q == 0) h1[(size_t)g * 16 + o] = fmaxf(acc + sA[1600 + o], 0.f);
}

// ---------------- K2: BN1 batch sums ----------------
__global__ __launch_bounds__(256) void k2_stats1(const float* __restrict__ h1,
                                                 float* __restrict__ ws) {
    __shared__ float ps[32];
    int tid = threadIdx.x;
    if (tid < 32) ps[tid] = 0.f;
    __syncthreads();
    int c = tid & 15;
    float s = 0.f, sq = 0.f;
    for (int i = blockIdx.x * blockDim.x + tid; i < NGRAPH * 16; i += gridDim.x * blockDim.x) {
        float v = h1[i];
        s += v; sq += v * v;
    }
    atomicAdd(&ps[c], s);
    atomicAdd(&ps[16 + c], sq);
    __syncthreads();
    if (tid < 32) atomicAdd(&ws[WS_ST1 + tid], ps[tid]);
}

// ---------------- K3: fold BN1 into fc2 ----------------
__global__ void k3_fold1(const float* __restrict__ fc2w, const float* __restrict__ fc2b,
                         const float* __restrict__ g1, const float* __restrict__ b1,
                         float* __restrict__ ws) {
    __shared__ float s1[16], t1[16];
    int tid = threadIdx.x;
    if (tid < 16) {
        float m = ws[WS_ST1 + tid] / (float)NGRAPH;
        float v = ws[WS_ST1 + 16 + tid] / (float)NGRAPH - m * m;
        float sc = g1[tid] * rsqrtf(v + BN_EPS);
        s1[tid] = sc;
        t1[tid] = b1[tid] - m * sc;
    }
    __syncthreads();
    for (int idx = tid; idx < 512; idx += blockDim.x) {
        int i = idx >> 5;
        ws[WS_W2 + idx] = s1[i] * fc2w[idx];
    }
    if (tid < 32) {
        float a = fc2b[tid];
        for (int i = 0; i < 16; i++) a += t1[i] * fc2w[i * 32 + tid];
        ws[WS_B2 + tid] = a;
    }
}

// ---------------- K4: fc2 + relu -> BN2 sums only ----------------
__global__ __launch_bounds__(256) void k4_fc2(const float* __restrict__ h1,
                                              float* __restrict__ ws) {
    __shared__ float w2[512];
    __shared__ float b2[32];
    __shared__ float pSum[32], pSq[32];
    int tid = threadIdx.x;
    for (int i = tid; i < 512; i += 256) w2[i] = ws[WS_W2 + i];
    if (tid < 32) {
        b2[tid] = ws[WS_B2 + tid];
        pSum[tid] = 0.f;
        pSq[tid] = 0.f;
    }
    __syncthreads();
    int g = blockIdx.x * blockDim.x + tid;
    int lane = tid & 63;
    const float4* h4 = (const float4*)(h1 + (size_t)g * 16);
    float4 a0 = h4[0], a1 = h4[1], a2 = h4[2], a3 = h4[3];
    float hin[16] = {a0.x, a0.y, a0.z, a0.w, a1.x, a1.y, a1.z, a1.w,
                     a2.x, a2.y, a2.z, a2.w, a3.x, a3.y, a3.z, a3.w};
    for (int o = 0; o < 32; o++) {
        float acc = b2[o];
        #pragma unroll
        for (int i = 0; i < 16; i++) acc += hin[i] * w2[i * 32 + o];
        acc = fmaxf(acc, 0.f);
        float v = acc, v2 = acc * acc;
        #pragma unroll
        for (int off = 32; off; off >>= 1) {
            v += __shfl_xor(v, off);
            v2 += __shfl_xor(v2, off);
        }
        if (lane == 0) {
            atomicAdd(&pSum[o], v);
            atomicAdd(&pSq[o], v2);
        }
    }
    __syncthreads();
    if (tid < 32) {
        atomicAdd(&ws[WS_ST2 + tid], pSum[tid]);
        atomicAdd(&ws[WS_ST2 + 32 + tid], pSq[tid]);
    }
}

// ---------------- K5: fold BN2 into fc3 ----------------
__global__ void k5_fold2(const float* __restrict__ fc3w, const float* __restrict__ fc3b,
                         const float* __restrict__ g2, const float* __restrict__ b2,
                         float* __restrict__ ws) {
    __shared__ float s2[32], t2[32];
    int tid = threadIdx.x;
    if (tid < 32) {
        float m = ws[WS_ST2 + tid] / (float)NGRAPH;
        float v = ws[WS_ST2 + 32 + tid] / (float)NGRAPH - m * m;
        float sc = g2[tid] * rsqrtf(v + BN_EPS);
        s2[tid] = sc;
        t2[tid] = b2[tid] - m * sc;
    }
    __syncthreads();
    if (tid < 64) {
        int i = tid >> 1;
        ws[WS_W3 + tid] = s2[i] * fc3w[tid];
    }
    if (tid < 2) {
        float a = fc3b[tid];
        for (int i = 0; i < 32; i++) a += t2[i] * fc3w[i * 2 + tid];
        ws[WS_B3 + tid] = a;
    }
}

// ---------------- K6: recompute fc2+relu, fc3 -> fp32 output [B,2] ----------------
__global__ __launch_bounds__(256) void k6_out(const float* __restrict__ h1,
                                              const float* __restrict__ ws,
                                              float2* __restrict__ out) {
    __shared__ float w2[512];
    __shared__ float b2[32];
    __shared__ float w3[64];
    __shared__ float b3[2];
    int tid = threadIdx.x;
    for (int i = tid; i < 512; i += 256) w2[i] = ws[WS_W2 + i];
    if (tid < 32) b2[tid] = ws[WS_B2 + tid];
    if (tid >= 64 && tid < 128) w3[tid - 64] = ws[WS_W3 + (tid - 64)];
    if (tid >= 128 && tid < 130) b3[tid - 128] = ws[WS_B3 + (tid - 128)];
    __syncthreads();
    int g = blockIdx.x * blockDim.x + tid;
    const float4* h4 = (const float4*)(h1 + (size_t)g * 16);
    float4 a0 = h4[0], a1 = h4[1], a2 = h4[2], a3 = h4[3];
    float hin[16] = {a0.x, a0.y, a0.z, a0.w, a1.x, a1.y, a1.z, a1.w,
                     a2.x, a2.y, a2.z, a2.w, a3.x, a3.y, a3.z, a3.w};
    float z0 = b3[0], z1 = b3[1];
    for (int o = 0; o < 32; o++) {
        float acc = b2[o];
        #pragma unroll
        for (int i = 0; i < 16; i++) acc += hin[i] * w2[i * 32 + o];
        acc = fmaxf(acc, 0.f);
        z0 += acc * w3[o * 2];
        z1 += acc * w3[o * 2 + 1];
    }
    out[g] = make_float2(z0, z1);
}

extern "C" void kernel_launch(void* const* d_in, const int* in_sizes, int n_in,
                              void* d_out, int out_size, void* d_ws, size_t ws_size,
                              hipStream_t stream) {
    (void)in_sizes; (void)n_in; (void)out_size; (void)ws_size;
    const float* x = (const float*)d_in[0];
    const int* edges = (const int*)d_in[1];
    Params12 wp;
    for (int i = 0; i < 12; i++) wp.p[i] = (const float*)d_in[2 + i];
    const float* fc1w = (const float*)d_in[14];
    const float* fc1b = (const float*)d_in[15];
    const float* bn1g = (const float*)d_in[16];
    const float* bn1b = (const float*)d_in[17];
    const float* fc2w = (const float*)d_in[18];
    const float* fc2b = (const float*)d_in[19];
    const float* bn2g = (const float*)d_in[20];
    const float* bn2b = (const float*)d_in[21];
    const float* fc3w = (const float*)d_in[22];
    const float* fc3b = (const float*)d_in[23];

    float* ws = (float*)d_ws;
    float* h1 = ws + WS_H1;

    k0_pre<<<1, 256, 0, stream>>>(wp, fc1w, fc1b, ws);
    k1_gcn<<<NGRAPH / GPB, 256, 0, stream>>>(x, edges, ws, h1);
    k2_stats1<<<256, 256, 0, stream>>>(h1, ws);
    k3_fold1<<<1, 256, 0, stream>>>(fc2w, fc2b, bn1g, bn1b, ws);
    k4_fc2<<<NGRAPH / 256, 256, 0, stream>>>(h1, ws);
    k5_fold2<<<1, 64, 0, stream>>>(fc3w, fc3b, bn2g, bn2b, ws);
    k6_out<<<NGRAPH / 256, 256, 0, stream>>>(h1, ws, (float2*)d_out);
}

// Round 4
// 280.132 us; speedup vs baseline: 1.5492x; 1.5492x over previous
//
#include <hip/hip_runtime.h>

#define NPG 50
#define EPG 400
#define NGRAPH 32768
#define NNODE (NGRAPH * NPG)
#define NEDGE (NGRAPH * EPG)
#define BN_EPS 1e-5f

// ---- workspace layout (float offsets) ----
#define WS_A1 0            // [800]  A1[50][16]
#define WS_A2 800          // [800]  A2[50][16]
#define WS_K0 1600         // [16]   const + fc1_b
#define WS_ST1 1616        // [32]   sum[16], sumsq[16] for BN1
#define WS_W2 1648         // [512]  folded fc2 weights [16][32]
#define WS_B2 2160         // [32]   folded fc2 bias
#define WS_ST2 2192        // [64]   sum[32], sumsq[32] for BN2
#define WS_W3 2256         // [64]   folded fc3 weights [32][2]
#define WS_B3 2320         // [2]    folded fc3 bias
#define WS_CNT1 2324       // [1]    block counter for k23 fold (as uint)
#define WS_CNT2 2325       // [1]    block counter for k45 fold (as uint)
#define WS_H1 4096         // [NGRAPH*16] fp32

__global__ void FullGCN_52286931861996_kernel() {}

struct Params12 { const float* p[12]; };

__device__ __forceinline__ float rdlane(float v, int s) {
    return __uint_as_float(__builtin_amdgcn_readlane(__float_as_uint(v), s));
}

// ---------------- K0: precompute A1/A2/K0vec, zero accumulators ----------------
__global__ void k0_pre(Params12 wp, const float* __restrict__ fc1w,
                       const float* __restrict__ fc1b, float* __restrict__ ws) {
    __shared__ float U[12], C[12], Bc[12];
    int tid = threadIdx.x;
    if (tid < 12) {
        int b = tid >> 2, j = tid & 3;
        const float* W1 = wp.p[b * 4 + 0];
        const float* b1 = wp.p[b * 4 + 1];
        const float* W2 = wp.p[b * 4 + 2];
        const float* b2 = wp.p[b * 4 + 3];
        float u = 0.f, c = 0.f;
        for (int k = 0; k < 4; k++) {
            float w2 = W2[k * 4 + j];
            u += W1[k] * w2;
            c += b1[k] * w2;
        }
        U[tid] = u; C[tid] = c; Bc[tid] = b2[j];
    }
    __syncthreads();
    for (int idx = tid; idx < 1600; idx += blockDim.x) {
        int which = (idx >= 800);
        int e = which ? idx - 800 : idx;
        int n = e >> 4, o = e & 15;
        const float* V = which ? C : U;
        float a = 0.f;
        for (int f = 0; f < 12; f++) a += V[f] * fc1w[(n * 12 + f) * 16 + o];
        ws[idx] = a;
    }
    if (tid < 16) {
        float a = fc1b[tid];
        for (int n = 0; n < NPG; n++)
            for (int f = 0; f < 12; f++)
                a += Bc[f] * fc1w[(n * 12 + f) * 16 + tid];
        ws[WS_K0 + tid] = a;
    }
    if (tid < 32) ws[WS_ST1 + tid] = 0.f;
    if (tid >= 64 && tid < 128) ws[WS_ST2 + (tid - 64)] = 0.f;
    if (tid == 200) { ((unsigned int*)ws)[WS_CNT1] = 0u; ((unsigned int*)ws)[WS_CNT2] = 0u; }
}

// ---------------- K1: per-graph GCN via dense u8 count matrix ----------------
// C[d][s] = multiplicity of edge s->d. Row stride 68 bytes (17 words, odd -> <=2-way banks).
// 64 rows allocated (rows 50..63 stay zero). 1088 words = 4352 B per graph.
#define GPB 4
#define CROWW 17        // row stride in words
#define CWORDS 1088     // 64*17
__global__ __launch_bounds__(256) void k1_gcn(const float* __restrict__ x,
                                              const int* __restrict__ edges,
                                              const float* __restrict__ ws,
                                              float* __restrict__ h1) {
    __shared__ float sA[1616];                 // A1 | A2 | K0
    __shared__ unsigned int sC[GPB][CWORDS];   // count matrices
    __shared__ float sOut[GPB][128];           // ppx[0..63] | r[0..63]

    int tid = threadIdx.x;
    for (int i = tid; i < 1616; i += 256) sA[i] = ws[i];

    int w = tid >> 6, lane = tid & 63;
    int g = blockIdx.x * GPB + w;
    int nb = g * NPG;
    unsigned int* sCw = &sC[w][0];

    // zero own C (uint4 = 272 slots)
    {
        uint4 z4 = make_uint4(0u, 0u, 0u, 0u);
        uint4* cz = (uint4*)sCw;
        #pragma unroll
        for (int i = 0; i < 4; i++) cz[lane + i * 64] = z4;
        if (lane < 16) cz[lane + 256] = z4;
    }

    float xv = (lane < NPG) ? x[nb + lane] : 0.f;

    // load this graph's edges: row0 = src, row1 = dst, 100 int4 each
    const int4* s4 = (const int4*)edges;
    const int4* d4 = s4 + (NEDGE / 4);
    int base = g * (EPG / 4);
    int4 sa = s4[base + lane];
    int4 da = d4[base + lane];
    bool m2 = (64 + lane) < (EPG / 4);
    int4 sb = make_int4(0, 0, 0, 0), db = make_int4(0, 0, 0, 0);
    if (m2) { sb = s4[base + 64 + lane]; db = d4[base + 64 + lane]; }

    __syncthreads();  // sA staged + own C zeroed (C private to wave, but one barrier is cheap)

    // scatter: C[dst][src] += 1 (packed u8 in u32 words)
    {
        int sl[8], dl[8];
        sl[0] = sa.x - nb; sl[1] = sa.y - nb; sl[2] = sa.z - nb; sl[3] = sa.w - nb;
        dl[0] = da.x - nb; dl[1] = da.y - nb; dl[2] = da.z - nb; dl[3] = da.w - nb;
        sl[4] = sb.x - nb; sl[5] = sb.y - nb; sl[6] = sb.z - nb; sl[7] = sb.w - nb;
        dl[4] = db.x - nb; dl[5] = db.y - nb; dl[6] = db.z - nb; dl[7] = db.w - nb;
        #pragma unroll
        for (int e = 0; e < 4; e++) {
            int cell = dl[e] * 68 + sl[e];
            atomicAdd(&sCw[cell >> 2], 1u << ((cell & 3) * 8));
        }
        if (m2) {
            #pragma unroll
            for (int e = 4; e < 8; e++) {
                int cell = dl[e] * 68 + sl[e];
                atomicAdd(&sCw[cell >> 2], 1u << ((cell & 3) * 8));
            }
        }
    }
    __syncthreads();  // ensure all scatters of this wave visible (DS in-order per wave; barrier also stops compiler reordering)

    // read own row (cols 0..49 live in words 0..12; bytes 50+ are zero)
    unsigned int wv[13];
    #pragma unroll
    for (int k = 0; k < 13; k++) wv[k] = sCw[lane * CROWW + k];

    int deg = 1;
    #pragma unroll
    for (int k = 0; k < 13; k++) {
        unsigned int q = wv[k];
        deg += (q & 0xFFu) + ((q >> 8) & 0xFFu) + ((q >> 16) & 0xFFu) + (q >> 24);
    }
    float dinv = rsqrtf((float)deg);
    float dd = dinv * dinv;
    float vs = dinv * xv;

    // matvec 1 (dual RHS): px = P@x, r = P@1
    float pxa = 0.f, ra = 0.f;
    #pragma unroll
    for (int s = 0; s < NPG; s++) {
        float cnt = (float)((wv[s >> 2] >> ((s & 3) * 8)) & 0xFFu);
        pxa += cnt * rdlane(vs, s);
        ra  += cnt * rdlane(dinv, s);
    }
    float px = dinv * pxa + dd * xv;
    float rr = dinv * ra + dd;

    // matvec 2: ppx = P@px
    float vs2 = dinv * px;
    float ppa = 0.f;
    #pragma unroll
    for (int s = 0; s < NPG; s++) {
        float cnt = (float)((wv[s >> 2] >> ((s & 3) * 8)) & 0xFFu);
        ppa += cnt * rdlane(vs2, s);
    }
    float ppx = dinv * ppa + dd * px;

    sOut[w][lane] = ppx;
    sOut[w][64 + lane] = rr;
    // same-wave write->read: DS ops in order per wave, no barrier needed

    // z1[o] = sum_n ppx[n]*A1[n][o] + r[n]*A2[n][o] + K0[o]; relu; store
    int o = lane >> 2, q = lane & 3;
    float acc = 0.f;
    for (int n = q; n < NPG; n += 4)
        acc += sOut[w][n] * sA[n * 16 + o] + sOut[w][64 + n] * sA[800 + n * 16 + o];
    acc += __shfl_down(acc, 2, 4);
    acc += __shfl_down(acc, 1, 4);
    if (q == 0) h1[(size_t)g * 16 + o] = fmaxf(acc + sA[1600 + o], 0.f);
}

// ---------------- K23: BN1 batch sums + last-block folds BN1 into fc2 ----------------
__global__ __launch_bounds__(256) void k23_stats_fold(const float* __restrict__ h1,
                                                      const float* __restrict__ fc2w,
                                                      const float* __restrict__ fc2b,
                                                      const float* __restrict__ g1,
                                                      const float* __restrict__ b1,
                                                      float* __restrict__ ws) {
    __shared__ float ps[32];
    __shared__ int last;
    int tid = threadIdx.x;
    if (tid < 32) ps[tid] = 0.f;
    __syncthreads();
    int c = tid & 15;
    float s = 0.f, sq = 0.f;
    for (int i = blockIdx.x * blockDim.x + tid; i < NGRAPH * 16; i += gridDim.x * blockDim.x) {
        float v = h1[i];
        s += v; sq += v * v;
    }
    atomicAdd(&ps[c], s);
    atomicAdd(&ps[16 + c], sq);
    __syncthreads();
    if (tid < 32) atomicAdd(&ws[WS_ST1 + tid], ps[tid]);
    __threadfence();
    if (tid == 0)
        last = (atomicAdd(&((unsigned int*)ws)[WS_CNT1], 1u) == (unsigned int)(gridDim.x - 1));
    __syncthreads();
    if (!last) return;
    __threadfence();
    __shared__ float s1[16], t1[16];
    if (tid < 16) {
        float m  = atomicAdd(&ws[WS_ST1 + tid], 0.f) / (float)NGRAPH;
        float v  = atomicAdd(&ws[WS_ST1 + 16 + tid], 0.f) / (float)NGRAPH - m * m;
        float sc = g1[tid] * rsqrtf(v + BN_EPS);
        s1[tid] = sc;
        t1[tid] = b1[tid] - m * sc;
    }
    __syncthreads();
    for (int idx = tid; idx < 512; idx += blockDim.x)
        ws[WS_W2 + idx] = s1[idx >> 5] * fc2w[idx];
    if (tid < 32) {
        float a = fc2b[tid];
        for (int i = 0; i < 16; i++) a += t1[i] * fc2w[i * 32 + tid];
        ws[WS_B2 + tid] = a;
    }
}

// ---------------- K45: fc2+relu -> BN2 sums; last block folds BN2 into fc3 ----------------
__global__ __launch_bounds__(256) void k45_fc2_fold(const float* __restrict__ h1,
                                                    const float* __restrict__ fc3w,
                                                    const float* __restrict__ fc3b,
                                                    const float* __restrict__ g2,
                                                    const float* __restrict__ b2g,
                                                    float* __restrict__ ws) {
    __shared__ float w2[512];
    __shared__ float b2[32];
    __shared__ float pSum[32], pSq[32];
    __shared__ int last;
    int tid = threadIdx.x;
    for (int i = tid; i < 512; i += 256) w2[i] = ws[WS_W2 + i];
    if (tid < 32) {
        b2[tid] = ws[WS_B2 + tid];
        pSum[tid] = 0.f;
        pSq[tid] = 0.f;
    }
    __syncthreads();
    int g = blockIdx.x * blockDim.x + tid;
    int lane = tid & 63;
    const float4* h4 = (const float4*)(h1 + (size_t)g * 16);
    float4 a0 = h4[0], a1 = h4[1], a2 = h4[2], a3 = h4[3];
    float hin[16] = {a0.x, a0.y, a0.z, a0.w, a1.x, a1.y, a1.z, a1.w,
                     a2.x, a2.y, a2.z, a2.w, a3.x, a3.y, a3.z, a3.w};
    for (int o = 0; o < 32; o++) {
        float acc = b2[o];
        #pragma unroll
        for (int i = 0; i < 16; i++) acc += hin[i] * w2[i * 32 + o];
        acc = fmaxf(acc, 0.f);
        float v = acc, v2 = acc * acc;
        #pragma unroll
        for (int off = 32; off; off >>= 1) {
            v += __shfl_xor(v, off);
            v2 += __shfl_xor(v2, off);
        }
        if (lane == 0) {
            atomicAdd(&pSum[o], v);
            atomicAdd(&pSq[o], v2);
        }
    }
    __syncthreads();
    if (tid < 32) {
        atomicAdd(&ws[WS_ST2 + tid], pSum[tid]);
        atomicAdd(&ws[WS_ST2 + 32 + tid], pSq[tid]);
    }
    __threadfence();
    if (tid == 0)
        last = (atomicAdd(&((unsigned int*)ws)[WS_CNT2], 1u) == (unsigned int)(gridDim.x - 1));
    __syncthreads();
    if (!last) return;
    __threadfence();
    __shared__ float s2[32], t2[32];
    if (tid < 32) {
        float m  = atomicAdd(&ws[WS_ST2 + tid], 0.f) / (float)NGRAPH;
        float v  = atomicAdd(&ws[WS_ST2 + 32 + tid], 0.f) / (float)NGRAPH - m * m;
        float sc = g2[tid] * rsqrtf(v + BN_EPS);
        s2[tid] = sc;
        t2[tid] = b2g[tid] - m * sc;
    }
    __syncthreads();
    if (tid < 64) ws[WS_W3 + tid] = s2[tid >> 1] * fc3w[tid];
    if (tid < 2) {
        float a = fc3b[tid];
        for (int i = 0; i < 32; i++) a += t2[i] * fc3w[i * 2 + tid];
        ws[WS_B3 + tid] = a;
    }
}

// ---------------- K6: recompute fc2+relu, fc3 -> fp32 output [B,2] ----------------
__global__ __launch_bounds__(256) void k6_out(const float* __restrict__ h1,
                                              const float* __restrict__ ws,
                                              float2* __restrict__ out) {
    __shared__ float w2[512];
    __shared__ float b2[32];
    __shared__ float w3[64];
    __shared__ float b3[2];
    int tid = threadIdx.x;
    for (int i = tid; i < 512; i += 256) w2[i] = ws[WS_W2 + i];
    if (tid < 32) b2[tid] = ws[WS_B2 + tid];
    if (tid >= 64 && tid < 128) w3[tid - 64] = ws[WS_W3 + (tid - 64)];
    if (tid >= 128 && tid < 130) b3[tid - 128] = ws[WS_B3 + (tid - 128)];
    __syncthreads();
    int g = blockIdx.x * blockDim.x + tid;
    const float4* h4 = (const float4*)(h1 + (size_t)g * 16);
    float4 a0 = h4[0], a1 = h4[1], a2 = h4[2], a3 = h4[3];
    float hin[16] = {a0.x, a0.y, a0.z, a0.w, a1.x, a1.y, a1.z, a1.w,
                     a2.x, a2.y, a2.z, a2.w, a3.x, a3.y, a3.z, a3.w};
    float z0 = b3[0], z1 = b3[1];
    for (int o = 0; o < 32; o++) {
        float acc = b2[o];
        #pragma unroll
        for (int i = 0; i < 16; i++) acc += hin[i] * w2[i * 32 + o];
        acc = fmaxf(acc, 0.f);
        z0 += acc * w3[o * 2];
        z1 += acc * w3[o * 2 + 1];
    }
    out[g] = make_float2(z0, z1);
}

extern "C" void kernel_launch(void* const* d_in, const int* in_sizes, int n_in,
                              void* d_out, int out_size, void* d_ws, size_t ws_size,
                              hipStream_t stream) {
    (void)in_sizes; (void)n_in; (void)out_size; (void)ws_size;
    const float* x = (const float*)d_in[0];
    const int* edges = (const int*)d_in[1];
    Params12 wp;
    for (int i = 0; i < 12; i++) wp.p[i] = (const float*)d_in[2 + i];
    const float* fc1w = (const float*)d_in[14];
    const float* fc1b = (const float*)d_in[15];
    const float* bn1g = (const float*)d_in[16];
    const float* bn1b = (const float*)d_in[17];
    const float* fc2w = (const float*)d_in[18];
    const float* fc2b = (const float*)d_in[19];
    const float* bn2g = (const float*)d_in[20];
    const float* bn2b = (const float*)d_in[21];
    const float* fc3w = (const float*)d_in[22];
    const float* fc3b = (const float*)d_in[23];

    float* ws = (float*)d_ws;
    float* h1 = ws + WS_H1;

    k0_pre<<<1, 256, 0, stream>>>(wp, fc1w, fc1b, ws);
    k1_gcn<<<NGRAPH / GPB, 256, 0, stream>>>(x, edges, ws, h1);
    k23_stats_fold<<<256, 256, 0, stream>>>(h1, fc2w, fc2b, bn1g, bn1b, ws);
    k45_fc2_fold<<<NGRAPH / 256, 256, 0, stream>>>(h1, fc3w, fc3b, bn2g, bn2b, ws);
    k6_out<<<NGRAPH / 256, 256, 0, stream>>>(h1, ws, (float2*)d_out);
}

// Round 5
// 277.848 us; speedup vs baseline: 1.5619x; 1.0082x over previous
//
#include <hip/hip_runtime.h>

#define NPG 50
#define EPG 400
#define NGRAPH 32768
#define NNODE (NGRAPH * NPG)
#define NEDGE (NGRAPH * EPG)
#define BN_EPS 1e-5f

// ---- workspace layout (float offsets) ----
#define WS_A1T 0           // [1280] A1t[l=0..63][k=0..19]  (o=l>>2, q=l&3, n=q+4k)
#define WS_A2T 1280        // [1280] A2t same layout
#define WS_K0 2560         // [16]
#define WS_ST1 2576        // [32]  sum[16], sumsq[16] for BN1
#define WS_W2 2608         // [512] folded fc2 weights [16][32]
#define WS_B2 3120         // [32]
#define WS_ST2 3152        // [64]  sum[32], sumsq[32] for BN2
#define WS_W3 3216         // [64]  folded fc3 weights [32][2]
#define WS_B3 3280         // [2]
#define WS_CNT1 3282       // uint index
#define WS_CNT2 3283       // uint index
#define WS_H1 4096         // [NGRAPH*16] fp32

__global__ void FullGCN_52286931861996_kernel() {}

struct Params12 { const float* p[12]; };

__device__ __forceinline__ float rdlane(float v, int s) {
    return __uint_as_float(__builtin_amdgcn_readlane(__float_as_uint(v), s));
}

// ---------------- K0: precompute A1t/A2t/K0vec (transposed padded layout) ----------------
__global__ void k0_pre(Params12 wp, const float* __restrict__ fc1w,
                       const float* __restrict__ fc1b, float* __restrict__ ws) {
    __shared__ float U[12], C[12], Bc[12];
    int tid = threadIdx.x;
    if (tid < 12) {
        int b = tid >> 2, j = tid & 3;
        const float* W1 = wp.p[b * 4 + 0];
        const float* b1 = wp.p[b * 4 + 1];
        const float* W2 = wp.p[b * 4 + 2];
        const float* b2 = wp.p[b * 4 + 3];
        float u = 0.f, c = 0.f;
        for (int k = 0; k < 4; k++) {
            float w2 = W2[k * 4 + j];
            u += W1[k] * w2;
            c += b1[k] * w2;
        }
        U[tid] = u; C[tid] = c; Bc[tid] = b2[j];
    }
    __syncthreads();
    // A1t[l*20+k] = sum_f U[f]*fc1w[(n*12+f)*16+o], n=(l&3)+4k, o=l>>2 (0 if k>=13 or n>=50)
    for (int idx = tid; idx < 2560; idx += blockDim.x) {
        int which = (idx >= 1280);
        int e = which ? idx - 1280 : idx;
        int l = e / 20, k = e % 20;
        int o = l >> 2, n = (l & 3) + 4 * k;
        const float* V = which ? C : U;
        float a = 0.f;
        if (k < 13 && n < NPG)
            for (int f = 0; f < 12; f++) a += V[f] * fc1w[(n * 12 + f) * 16 + o];
        ws[idx] = a;
    }
    if (tid < 16) {
        float a = fc1b[tid];
        for (int n = 0; n < NPG; n++)
            for (int f = 0; f < 12; f++)
                a += Bc[f] * fc1w[(n * 12 + f) * 16 + tid];
        ws[WS_K0 + tid] = a;
    }
    if (tid < 32) ws[WS_ST1 + tid] = 0.f;
    if (tid >= 64 && tid < 128) ws[WS_ST2 + (tid - 64)] = 0.f;
    if (tid == 200) { ((unsigned int*)ws)[WS_CNT1] = 0u; ((unsigned int*)ws)[WS_CNT2] = 0u; }
}

// ---------------- K1: per-graph GCN via dense u8 count matrix ----------------
// C[d][s] = multiplicity of edge s->d; row stride 68 B (17 words, odd -> 2-way banks = free).
#define GPB 4
#define CROWW 17
#define CWORDS 1088
__global__ __launch_bounds__(256) void k1_gcn(const float* __restrict__ x,
                                              const int* __restrict__ edges,
                                              const float* __restrict__ ws,
                                              float* __restrict__ h1) {
    __shared__ float4 sA4[644];                // A1t[1280] | A2t[1280] | K0[16] (floats)
    __shared__ unsigned int sC[GPB][CWORDS];
    __shared__ float2 sOut[GPB][64];           // {ppx, r} per node
    float* sA = (float*)sA4;

    int tid = threadIdx.x;
    // stage header as float4 (ds_write_b128)
    {
        const float4* wsv = (const float4*)ws;
        #pragma unroll
        for (int i = 0; i < 3; i++) {
            int j = tid + i * 256;
            if (j < 644) sA4[j] = wsv[j];
        }
    }

    int w = tid >> 6, lane = tid & 63;
    int g = blockIdx.x * GPB + w;
    int nb = g * NPG;
    unsigned int* sCw = &sC[w][0];

    // zero words 0..1023 (covers all rows < 50; rows >=50 are junk-but-unused)
    {
        uint4 z = make_uint4(0u, 0u, 0u, 0u);
        uint4* cz = (uint4*)sCw;
        #pragma unroll
        for (int i = 0; i < 4; i++) cz[lane + i * 64] = z;
    }

    float xv = (lane < NPG) ? x[nb + lane] : 0.f;

    // load this graph's edges: row0 = src, row1 = dst, 100 int4 each
    const int4* s4 = (const int4*)edges;
    const int4* d4 = s4 + (NEDGE / 4);
    int base = g * (EPG / 4);
    int4 sa = s4[base + lane];
    int4 da = d4[base + lane];
    bool m2 = lane < (EPG / 4 - 64);
    int4 sb = make_int4(0, 0, 0, 0), db = make_int4(0, 0, 0, 0);
    if (m2) { sb = s4[base + 64 + lane]; db = d4[base + 64 + lane]; }

    // scatter: C[dst][src] += 1 (u8 packed; wave-private C, DS in-order -> no barrier)
    {
        int sl[8], dl[8];
        sl[0] = sa.x - nb; sl[1] = sa.y - nb; sl[2] = sa.z - nb; sl[3] = sa.w - nb;
        dl[0] = da.x - nb; dl[1] = da.y - nb; dl[2] = da.z - nb; dl[3] = da.w - nb;
        sl[4] = sb.x - nb; sl[5] = sb.y - nb; sl[6] = sb.z - nb; sl[7] = sb.w - nb;
        dl[4] = db.x - nb; dl[5] = db.y - nb; dl[6] = db.z - nb; dl[7] = db.w - nb;
        #pragma unroll
        for (int e = 0; e < 4; e++) {
            int cell = dl[e] * 68 + sl[e];
            atomicAdd(&sCw[cell >> 2], 1u << ((cell & 3) * 8));
        }
        if (m2) {
            #pragma unroll
            for (int e = 4; e < 8; e++) {
                int cell = dl[e] * 68 + sl[e];
                atomicAdd(&sCw[cell >> 2], 1u << ((cell & 3) * 8));
            }
        }
    }

    // read own row (cols 0..49 in words 0..12)
    unsigned int wv[13];
    #pragma unroll
    for (int k = 0; k < 13; k++) wv[k] = sCw[lane * CROWW + k];

    // deg via packed 16-bit halves
    unsigned int acc2 = 0;
    #pragma unroll
    for (int k = 0; k < 13; k++)
        acc2 += (wv[k] & 0x00FF00FFu) + ((wv[k] >> 8) & 0x00FF00FFu);
    int deg = 1 + (int)((acc2 & 0xFFFFu) + (acc2 >> 16));
    float dinv = rsqrtf((float)deg);
    float dd = dinv * dinv;
    float vs = dinv * xv;

    // matvec 1 (dual RHS): px = P@x, r = P@1
    float pxa = 0.f, ra = 0.f;
    #pragma unroll
    for (int s = 0; s < NPG; s++) {
        float cnt = (float)((wv[s >> 2] >> ((s & 3) * 8)) & 0xFFu);
        pxa += cnt * rdlane(vs, s);
        ra  += cnt * rdlane(dinv, s);
    }
    float px = dinv * pxa + dd * xv;
    float rr = dinv * ra + dd;

    // matvec 2: ppx = P@px
    float vs2 = dinv * px;
    float ppa = 0.f;
    #pragma unroll
    for (int s = 0; s < NPG; s++) {
        float cnt = (float)((wv[s >> 2] >> ((s & 3) * 8)) & 0xFFu);
        ppa += cnt * rdlane(vs2, s);
    }
    float ppx = dinv * ppa + dd * px;

    if (lane >= NPG) { ppx = 0.f; rr = 0.f; }
    sOut[w][lane] = make_float2(ppx, rr);

    __syncthreads();  // the ONLY barrier: sA (cross-wave) must be staged before epilogue reads

    // epilogue: lane l accumulates o=l>>2 over n = (l&3)+4k
    int o = lane >> 2, q = lane & 3;
    const float* a1p = sA + lane * 20;
    const float* a2p = sA + 1280 + lane * 20;
    float4 c0 = ((const float4*)a1p)[0], c1 = ((const float4*)a1p)[1], c2 = ((const float4*)a1p)[2];
    float  c3 = a1p[12];
    float4 d0 = ((const float4*)a2p)[0], d1 = ((const float4*)a2p)[1], d2 = ((const float4*)a2p)[2];
    float  d3 = a2p[12];
    float A1r[13] = {c0.x, c0.y, c0.z, c0.w, c1.x, c1.y, c1.z, c1.w, c2.x, c2.y, c2.z, c2.w, c3};
    float A2r[13] = {d0.x, d0.y, d0.z, d0.w, d1.x, d1.y, d1.z, d1.w, d2.x, d2.y, d2.z, d2.w, d3};
    float accz = 0.f;
    #pragma unroll
    for (int k = 0; k < 13; k++) {
        float2 pr = sOut[w][q + 4 * k];
        accz += pr.x * A1r[k] + pr.y * A2r[k];
    }
    accz += __shfl_down(accz, 2, 4);
    accz += __shfl_down(accz, 1, 4);
    if (q == 0) h1[(size_t)g * 16 + o] = fmaxf(accz + sA[2560 + o], 0.f);
}

// ---------------- K23: BN1 batch sums + last-block folds BN1 into fc2 ----------------
__global__ __launch_bounds__(256) void k23_stats_fold(const float* __restrict__ h1,
                                                      const float* __restrict__ fc2w,
                                                      const float* __restrict__ fc2b,
                                                      const float* __restrict__ g1,
                                                      const float* __restrict__ b1,
                                                      float* __restrict__ ws) {
    __shared__ float ps[32];
    __shared__ int last;
    int tid = threadIdx.x;
    if (tid < 32) ps[tid] = 0.f;
    __syncthreads();
    int c = tid & 15;
    float s = 0.f, sq = 0.f;
    for (int i = blockIdx.x * blockDim.x + tid; i < NGRAPH * 16; i += gridDim.x * blockDim.x) {
        float v = h1[i];
        s += v; sq += v * v;
    }
    atomicAdd(&ps[c], s);
    atomicAdd(&ps[16 + c], sq);
    __syncthreads();
    if (tid < 32) atomicAdd(&ws[WS_ST1 + tid], ps[tid]);
    __threadfence();
    if (tid == 0)
        last = (atomicAdd(&((unsigned int*)ws)[WS_CNT1], 1u) == (unsigned int)(gridDim.x - 1));
    __syncthreads();
    if (!last) return;
    __threadfence();
    __shared__ float s1[16], t1[16];
    if (tid < 16) {
        float m  = atomicAdd(&ws[WS_ST1 + tid], 0.f) / (float)NGRAPH;
        float v  = atomicAdd(&ws[WS_ST1 + 16 + tid], 0.f) / (float)NGRAPH - m * m;
        float sc = g1[tid] * rsqrtf(v + BN_EPS);
        s1[tid] = sc;
        t1[tid] = b1[tid] - m * sc;
    }
    __syncthreads();
    for (int idx = tid; idx < 512; idx += blockDim.x)
        ws[WS_W2 + idx] = s1[idx >> 5] * fc2w[idx];
    if (tid < 32) {
        float a = fc2b[tid];
        for (int i = 0; i < 16; i++) a += t1[i] * fc2w[i * 32 + tid];
        ws[WS_B2 + tid] = a;
    }
}

// ---------------- K45: fc2+relu -> BN2 sums; last block folds BN2 into fc3 ----------------
__global__ __launch_bounds__(256) void k45_fc2_fold(const float* __restrict__ h1,
                                                    const float* __restrict__ fc3w,
                                                    const float* __restrict__ fc3b,
                                                    const float* __restrict__ g2,
                                                    const float* __restrict__ b2g,
                                                    float* __restrict__ ws) {
    __shared__ float w2[512];
    __shared__ float b2[32];
    __shared__ float pSum[32], pSq[32];
    __shared__ int last;
    int tid = threadIdx.x;
    for (int i = tid; i < 512; i += 256) w2[i] = ws[WS_W2 + i];
    if (tid < 32) {
        b2[tid] = ws[WS_B2 + tid];
        pSum[tid] = 0.f;
        pSq[tid] = 0.f;
    }
    __syncthreads();
    int g = blockIdx.x * blockDim.x + tid;
    int lane = tid & 63;
    const float4* h4 = (const float4*)(h1 + (size_t)g * 16);
    float4 a0 = h4[0], a1 = h4[1], a2 = h4[2], a3 = h4[3];
    float hin[16] = {a0.x, a0.y, a0.z, a0.w, a1.x, a1.y, a1.z, a1.w,
                     a2.x, a2.y, a2.z, a2.w, a3.x, a3.y, a3.z, a3.w};
    for (int o = 0; o < 32; o++) {
        float acc = b2[o];
        #pragma unroll
        for (int i = 0; i < 16; i++) acc += hin[i] * w2[i * 32 + o];
        acc = fmaxf(acc, 0.f);
        float v = acc, v2 = acc * acc;
        #pragma unroll
        for (int off = 32; off; off >>= 1) {
            v += __shfl_xor(v, off);
            v2 += __shfl_xor(v2, off);
        }
        if (lane == 0) {
            atomicAdd(&pSum[o], v);
            atomicAdd(&pSq[o], v2);
        }
    }
    __syncthreads();
    if (tid < 32) {
        atomicAdd(&ws[WS_ST2 + tid], pSum[tid]);
        atomicAdd(&ws[WS_ST2 + 32 + tid], pSq[tid]);
    }
    __threadfence();
    if (tid == 0)
        last = (atomicAdd(&((unsigned int*)ws)[WS_CNT2], 1u) == (unsigned int)(gridDim.x - 1));
    __syncthreads();
    if (!last) return;
    __threadfence();
    __shared__ float s2[32], t2[32];
    if (tid < 32) {
        float m  = atomicAdd(&ws[WS_ST2 + tid], 0.f) / (float)NGRAPH;
        float v  = atomicAdd(&ws[WS_ST2 + 32 + tid], 0.f) / (float)NGRAPH - m * m;
        float sc = g2[tid] * rsqrtf(v + BN_EPS);
        s2[tid] = sc;
        t2[tid] = b2g[tid] - m * sc;
    }
    __syncthreads();
    if (tid < 64) ws[WS_W3 + tid] = s2[tid >> 1] * fc3w[tid];
    if (tid < 2) {
        float a = fc3b[tid];
        for (int i = 0; i < 32; i++) a += t2[i] * fc3w[i * 2 + tid];
        ws[WS_B3 + tid] = a;
    }
}

// ---------------- K6: recompute fc2+relu, fc3 -> fp32 output [B,2] ----------------
__global__ __launch_bounds__(256) void k6_out(const float* __restrict__ h1,
                                              const float* __restrict__ ws,
                                              float2* __restrict__ out) {
    __shared__ float w2[512];
    __shared__ float b2[32];
    __shared__ float w3[64];
    __shared__ float b3[2];
    int tid = threadIdx.x;
    for (int i = tid; i < 512; i += 256) w2[i] = ws[WS_W2 + i];
    if (tid < 32) b2[tid] = ws[WS_B2 + tid];
    if (tid >= 64 && tid < 128) w3[tid - 64] = ws[WS_W3 + (tid - 64)];
    if (tid >= 128 && tid < 130) b3[tid - 128] = ws[WS_B3 + (tid - 128)];
    __syncthreads();
    int g = blockIdx.x * blockDim.x + tid;
    const float4* h4 = (const float4*)(h1 + (size_t)g * 16);
    float4 a0 = h4[0], a1 = h4[1], a2 = h4[2], a3 = h4[3];
    float hin[16] = {a0.x, a0.y, a0.z, a0.w, a1.x, a1.y, a1.z, a1.w,
                     a2.x, a2.y, a2.z, a2.w, a3.x, a3.y, a3.z, a3.w};
    float z0 = b3[0], z1 = b3[1];
    for (int o = 0; o < 32; o++) {
        float acc = b2[o];
        #pragma unroll
        for (int i = 0; i < 16; i++) acc += hin[i] * w2[i * 32 + o];
        acc = fmaxf(acc, 0.f);
        z0 += acc * w3[o * 2];
        z1 += acc * w3[o * 2 + 1];
    }
    out[g] = make_float2(z0, z1);
}

extern "C" void kernel_launch(void* const* d_in, const int* in_sizes, int n_in,
                              void* d_out, int out_size, void* d_ws, size_t ws_size,
                              hipStream_t stream) {
    (void)in_sizes; (void)n_in; (void)out_size; (void)ws_size;
    const float* x = (const float*)d_in[0];
    const int* edges = (const int*)d_in[1];
    Params12 wp;
    for (int i = 0; i < 12; i++) wp.p[i] = (const float*)d_in[2 + i];
    const float* fc1w = (const float*)d_in[14];
    const float* fc1b = (const float*)d_in[15];
    const float* bn1g = (const float*)d_in[16];
    const float* bn1b = (const float*)d_in[17];
    const float* fc2w = (const float*)d_in[18];
    const float* fc2b = (const float*)d_in[19];
    const float* bn2g = (const float*)d_in[20];
    const float* bn2b = (const float*)d_in[21];
    const float* fc3w = (const float*)d_in[22];
    const float* fc3b = (const float*)d_in[23];

    float* ws = (float*)d_ws;
    float* h1 = ws + WS_H1;

    k0_pre<<<1, 256, 0, stream>>>(wp, fc1w, fc1b, ws);
    k1_gcn<<<NGRAPH / GPB, 256, 0, stream>>>(x, edges, ws, h1);
    k23_stats_fold<<<256, 256, 0, stream>>>(h1, fc2w, fc2b, bn1g, bn1b, ws);
    k45_fc2_fold<<<NGRAPH / 256, 256, 0, stream>>>(h1, fc3w, fc3b, bn2g, bn2b, ws);
    k6_out<<<NGRAPH / 256, 256, 0, stream>>>(h1, ws, (float2*)d_out);
}

// Round 6
// 275.787 us; speedup vs baseline: 1.5736x; 1.0075x over previous
//
#include <hip/hip_runtime.h>

#define NPG 50
#define EPG 400
#define NGRAPH 32768
#define NNODE (NGRAPH * NPG)
#define NEDGE (NGRAPH * EPG)
#define BN_EPS 1e-5f

// ---- workspace layout (float offsets) ----
#define WS_A1T 0           // [1280] A1t[l=0..63][k=0..19]  (o=l>>2, q=l&3, n=q+4k), stride 20
#define WS_A2T 1280        // [1280] A2t same layout
#define WS_K0 2560         // [16]
#define WS_ST1 2576        // [32]  sum[16], sumsq[16] for BN1
#define WS_W2 2608         // [512] folded fc2 weights [16][32]
#define WS_B2 3120         // [32]
#define WS_ST2 3152        // [64]  sum[32], sumsq[32] for BN2
#define WS_W3 3216         // [64]  folded fc3 weights [32][2]
#define WS_B3 3280         // [2]
#define WS_CNT1 3282       // uint index
#define WS_CNT2 3283       // uint index
#define WS_H1 4096         // [NGRAPH*16] fp32

__global__ void FullGCN_52286931861996_kernel() {}

struct Params12 { const float* p[12]; };

__device__ __forceinline__ float rdlane(float v, int s) {
    return __uint_as_float(__builtin_amdgcn_readlane(__float_as_uint(v), s));
}

// ---------------- K0: precompute A1t/A2t/K0vec (transposed padded layout) ----------------
__global__ void k0_pre(Params12 wp, const float* __restrict__ fc1w,
                       const float* __restrict__ fc1b, float* __restrict__ ws) {
    __shared__ float U[12], C[12], Bc[12];
    int tid = threadIdx.x;
    if (tid < 12) {
        int b = tid >> 2, j = tid & 3;
        const float* W1 = wp.p[b * 4 + 0];
        const float* b1 = wp.p[b * 4 + 1];
        const float* W2 = wp.p[b * 4 + 2];
        const float* b2 = wp.p[b * 4 + 3];
        float u = 0.f, c = 0.f;
        for (int k = 0; k < 4; k++) {
            float w2 = W2[k * 4 + j];
            u += W1[k] * w2;
            c += b1[k] * w2;
        }
        U[tid] = u; C[tid] = c; Bc[tid] = b2[j];
    }
    __syncthreads();
    // A1t[l*20+k] = sum_f U[f]*fc1w[(n*12+f)*16+o], n=(l&3)+4k, o=l>>2 (0 if k>=13 or n>=50)
    for (int idx = tid; idx < 2560; idx += blockDim.x) {
        int which = (idx >= 1280);
        int e = which ? idx - 1280 : idx;
        int l = e / 20, k = e % 20;
        int o = l >> 2, n = (l & 3) + 4 * k;
        const float* V = which ? C : U;
        float a = 0.f;
        if (k < 13 && n < NPG)
            for (int f = 0; f < 12; f++) a += V[f] * fc1w[(n * 12 + f) * 16 + o];
        ws[idx] = a;
    }
    if (tid < 16) {
        float a = fc1b[tid];
        for (int n = 0; n < NPG; n++)
            for (int f = 0; f < 12; f++)
                a += Bc[f] * fc1w[(n * 12 + f) * 16 + tid];
        ws[WS_K0 + tid] = a;
    }
    if (tid < 32) ws[WS_ST1 + tid] = 0.f;
    if (tid >= 64 && tid < 128) ws[WS_ST2 + (tid - 64)] = 0.f;
    if (tid == 200) { ((unsigned int*)ws)[WS_CNT1] = 0u; ((unsigned int*)ws)[WS_CNT2] = 0u; }
}

// ---------------- K1: per-graph GCN via dense u8 count matrix (barrier-free) ----------------
// C[d][s] = multiplicity of edge s->d; row stride 13 words / 52 B (odd word stride -> <=2-way banks).
// A-matrices live in lane registers via global loads (L1-cached) -- no LDS staging, no barrier.
#define GPB 4
#define CROWW 13
#define CALLOC 840   // words allocated per graph (>= 63*13+12+1 = 832)
#define CZERO 168    // float4s zeroed per graph (covers words 0..671 >= last touched 649)
__global__ __launch_bounds__(256) void k1_gcn(const float* __restrict__ x,
                                              const int* __restrict__ edges,
                                              const float* __restrict__ ws,
                                              float* __restrict__ h1) {
    __shared__ unsigned int sC[GPB][CALLOC];
    __shared__ float2 sOut[GPB][64];           // {ppx, r} per node

    int tid = threadIdx.x;
    int w = tid >> 6, lane = tid & 63;
    int g = blockIdx.x * GPB + w;
    int nb = g * NPG;
    unsigned int* sCw = &sC[w][0];

    // zero the touched region of own C
    {
        uint4 z = make_uint4(0u, 0u, 0u, 0u);
        uint4* cz = (uint4*)sCw;
        #pragma unroll
        for (int i = 0; i < 3; i++) {
            int j = lane + i * 64;
            if (j < CZERO) cz[j] = z;
        }
    }

    float xv = (lane < NPG) ? x[nb + lane] : 0.f;

    // load this graph's edges: row0 = src, row1 = dst, 100 int4 each
    const int4* s4 = (const int4*)edges;
    const int4* d4 = s4 + (NEDGE / 4);
    int base = g * (EPG / 4);
    int4 sa = s4[base + lane];
    int4 da = d4[base + lane];
    bool m2 = lane < (EPG / 4 - 64);
    int4 sb = make_int4(0, 0, 0, 0), db = make_int4(0, 0, 0, 0);
    if (m2) { sb = s4[base + 64 + lane]; db = d4[base + 64 + lane]; }

    // scatter: C[dst][src] += 1 (u8 packed; wave-private C, DS in-order per wave -> no barrier)
    {
        int sl[8], dl[8];
        sl[0] = sa.x - nb; sl[1] = sa.y - nb; sl[2] = sa.z - nb; sl[3] = sa.w - nb;
        dl[0] = da.x - nb; dl[1] = da.y - nb; dl[2] = da.z - nb; dl[3] = da.w - nb;
        sl[4] = sb.x - nb; sl[5] = sb.y - nb; sl[6] = sb.z - nb; sl[7] = sb.w - nb;
        dl[4] = db.x - nb; dl[5] = db.y - nb; dl[6] = db.z - nb; dl[7] = db.w - nb;
        #pragma unroll
        for (int e = 0; e < 4; e++) {
            int cell = dl[e] * 52 + sl[e];
            atomicAdd(&sCw[cell >> 2], 1u << ((cell & 3) * 8));
        }
        if (m2) {
            #pragma unroll
            for (int e = 4; e < 8; e++) {
                int cell = dl[e] * 52 + sl[e];
                atomicAdd(&sCw[cell >> 2], 1u << ((cell & 3) * 8));
            }
        }
    }

    // read own row (cols 0..49 live in words 0..12)
    unsigned int wv[13];
    #pragma unroll
    for (int k = 0; k < 13; k++) wv[k] = sCw[lane * CROWW + k];

    // deg via packed 16-bit halves
    unsigned int acc2 = 0;
    #pragma unroll
    for (int k = 0; k < 13; k++)
        acc2 += (wv[k] & 0x00FF00FFu) + ((wv[k] >> 8) & 0x00FF00FFu);
    int deg = 1 + (int)((acc2 & 0xFFFFu) + (acc2 >> 16));
    float dinv = rsqrtf((float)deg);
    float dd = dinv * dinv;
    float vs = dinv * xv;

    // matvec 1 (dual RHS): px = P@x, r = P@1
    float pxa = 0.f, ra = 0.f;
    #pragma unroll
    for (int s = 0; s < NPG; s++) {
        float cnt = (float)((wv[s >> 2] >> ((s & 3) * 8)) & 0xFFu);
        pxa += cnt * rdlane(vs, s);
        ra  += cnt * rdlane(dinv, s);
    }
    float px = dinv * pxa + dd * xv;
    float rr = dinv * ra + dd;

    // matvec 2: ppx = P@px
    float vs2 = dinv * px;
    float ppa = 0.f;
    #pragma unroll
    for (int s = 0; s < NPG; s++) {
        float cnt = (float)((wv[s >> 2] >> ((s & 3) * 8)) & 0xFFu);
        ppa += cnt * rdlane(vs2, s);
    }
    float ppx = dinv * ppa + dd * px;

    if (lane >= NPG) { ppx = 0.f; rr = 0.f; }
    sOut[w][lane] = make_float2(ppx, rr);
    // same-wave LDS write->read: DS ops in order per wave, no barrier needed

    // A-rows for this lane from global (same 5 KB per wave -> L1-hot)
    const float4* a1v = (const float4*)(ws + lane * 20);
    const float4* a2v = (const float4*)(ws + 1280 + lane * 20);
    float4 c0 = a1v[0], c1 = a1v[1], c2 = a1v[2];
    float  c3 = ws[lane * 20 + 12];
    float4 d0 = a2v[0], d1 = a2v[1], d2 = a2v[2];
    float  d3 = ws[1280 + lane * 20 + 12];
    float k0v = ws[WS_K0 + (lane >> 2)];
    float A1r[13] = {c0.x, c0.y, c0.z, c0.w, c1.x, c1.y, c1.z, c1.w, c2.x, c2.y, c2.z, c2.w, c3};
    float A2r[13] = {d0.x, d0.y, d0.z, d0.w, d1.x, d1.y, d1.z, d1.w, d2.x, d2.y, d2.z, d2.w, d3};

    // epilogue: lane l accumulates o=l>>2 over n = (l&3)+4k
    int o = lane >> 2, q = lane & 3;
    float accz = 0.f;
    #pragma unroll
    for (int k = 0; k < 13; k++) {
        float2 pr = sOut[w][q + 4 * k];   // 4 distinct addrs/instr -> broadcast, conflict-free
        accz += pr.x * A1r[k] + pr.y * A2r[k];
    }
    accz += __shfl_down(accz, 2, 4);
    accz += __shfl_down(accz, 1, 4);
    if (q == 0) h1[(size_t)g * 16 + o] = fmaxf(accz + k0v, 0.f);
}

// ---------------- K23: BN1 batch sums + last-block folds BN1 into fc2 ----------------
__global__ __launch_bounds__(256) void k23_stats_fold(const float* __restrict__ h1,
                                                      const float* __restrict__ fc2w,
                                                      const float* __restrict__ fc2b,
                                                      const float* __restrict__ g1,
                                                      const float* __restrict__ b1,
                                                      float* __restrict__ ws) {
    __shared__ float ps[32];
    __shared__ int last;
    int tid = threadIdx.x;
    if (tid < 32) ps[tid] = 0.f;
    __syncthreads();
    int c = tid & 15;
    float s = 0.f, sq = 0.f;
    for (int i = blockIdx.x * blockDim.x + tid; i < NGRAPH * 16; i += gridDim.x * blockDim.x) {
        float v = h1[i];
        s += v; sq += v * v;
    }
    // wave pre-reduce: lanes with equal (lane&15) combine (xor 16, 32)
    s += __shfl_xor(s, 16); s += __shfl_xor(s, 32);
    sq += __shfl_xor(sq, 16); sq += __shfl_xor(sq, 32);
    if ((tid & 63) < 16) {
        atomicAdd(&ps[c], s);
        atomicAdd(&ps[16 + c], sq);
    }
    __syncthreads();
    if (tid < 32) atomicAdd(&ws[WS_ST1 + tid], ps[tid]);
    __threadfence();
    if (tid == 0)
        last = (atomicAdd(&((unsigned int*)ws)[WS_CNT1], 1u) == (unsigned int)(gridDim.x - 1));
    __syncthreads();
    if (!last) return;
    __threadfence();
    __shared__ float s1[16], t1[16];
    if (tid < 16) {
        float m  = atomicAdd(&ws[WS_ST1 + tid], 0.f) / (float)NGRAPH;
        float v  = atomicAdd(&ws[WS_ST1 + 16 + tid], 0.f) / (float)NGRAPH - m * m;
        float sc = g1[tid] * rsqrtf(v + BN_EPS);
        s1[tid] = sc;
        t1[tid] = b1[tid] - m * sc;
    }
    __syncthreads();
    for (int idx = tid; idx < 512; idx += blockDim.x)
        ws[WS_W2 + idx] = s1[idx >> 5] * fc2w[idx];
    if (tid < 32) {
        float a = fc2b[tid];
        for (int i = 0; i < 16; i++) a += t1[i] * fc2w[i * 32 + tid];
        ws[WS_B2 + tid] = a;
    }
}

// ---------------- K45: fc2+relu -> BN2 sums; last block folds BN2 into fc3 ----------------
__global__ __launch_bounds__(256) void k45_fc2_fold(const float* __restrict__ h1,
                                                    const float* __restrict__ fc3w,
                                                    const float* __restrict__ fc3b,
                                                    const float* __restrict__ g2,
                                                    const float* __restrict__ b2g,
                                                    float* __restrict__ ws) {
    __shared__ float w2[512];
    __shared__ float b2[32];
    __shared__ float pSum[32], pSq[32];
    __shared__ int last;
    int tid = threadIdx.x;
    for (int i = tid; i < 512; i += 256) w2[i] = ws[WS_W2 + i];
    if (tid < 32) {
        b2[tid] = ws[WS_B2 + tid];
        pSum[tid] = 0.f;
        pSq[tid] = 0.f;
    }
    __syncthreads();
    int g = blockIdx.x * blockDim.x + tid;
    int lane = tid & 63;
    const float4* h4 = (const float4*)(h1 + (size_t)g * 16);
    float4 a0 = h4[0], a1 = h4[1], a2 = h4[2], a3 = h4[3];
    float hin[16] = {a0.x, a0.y, a0.z, a0.w, a1.x, a1.y, a1.z, a1.w,
                     a2.x, a2.y, a2.z, a2.w, a3.x, a3.y, a3.z, a3.w};
    for (int o = 0; o < 32; o++) {
        float acc = b2[o];
        #pragma unroll
        for (int i = 0; i < 16; i++) acc += hin[i] * w2[i * 32 + o];
        acc = fmaxf(acc, 0.f);
        float v = acc, v2 = acc * acc;
        #pragma unroll
        for (int off = 32; off; off >>= 1) {
            v += __shfl_xor(v, off);
            v2 += __shfl_xor(v2, off);
        }
        if (lane == 0) {
            atomicAdd(&pSum[o], v);
            atomicAdd(&pSq[o], v2);
        }
    }
    __syncthreads();
    if (tid < 32) {
        atomicAdd(&ws[WS_ST2 + tid], pSum[tid]);
        atomicAdd(&ws[WS_ST2 + 32 + tid], pSq[tid]);
    }
    __threadfence();
    if (tid == 0)
        last = (atomicAdd(&((unsigned int*)ws)[WS_CNT2], 1u) == (unsigned int)(gridDim.x - 1));
    __syncthreads();
    if (!last) return;
    __threadfence();
    __shared__ float s2[32], t2[32];
    if (tid < 32) {
        float m  = atomicAdd(&ws[WS_ST2 + tid], 0.f) / (float)NGRAPH;
        float v  = atomicAdd(&ws[WS_ST2 + 32 + tid], 0.f) / (float)NGRAPH - m * m;
        float sc = g2[tid] * rsqrtf(v + BN_EPS);
        s2[tid] = sc;
        t2[tid] = b2g[tid] - m * sc;
    }
    __syncthreads();
    if (tid < 64) ws[WS_W3 + tid] = s2[tid >> 1] * fc3w[tid];
    if (tid < 2) {
        float a = fc3b[tid];
        for (int i = 0; i < 32; i++) a += t2[i] * fc3w[i * 2 + tid];
        ws[WS_B3 + tid] = a;
    }
}

// ---------------- K6: recompute fc2+relu, fc3 -> fp32 output [B,2] ----------------
__global__ __launch_bounds__(256) void k6_out(const float* __restrict__ h1,
                                              const float* __restrict__ ws,
                                              float2* __restrict__ out) {
    __shared__ float w2[512];
    __shared__ float b2[32];
    __shared__ float w3[64];
    __shared__ float b3[2];
    int tid = threadIdx.x;
    for (int i = tid; i < 512; i += 256) w2[i] = ws[WS_W2 + i];
    if (tid < 32) b2[tid] = ws[WS_B2 + tid];
    if (tid >= 64 && tid < 128) w3[tid - 64] = ws[WS_W3 + (tid - 64)];
    if (tid >= 128 && tid < 130) b3[tid - 128] = ws[WS_B3 + (tid - 128)];
    __syncthreads();
    int g = blockIdx.x * blockDim.x + tid;
    const float4* h4 = (const float4*)(h1 + (size_t)g * 16);
    float4 a0 = h4[0], a1 = h4[1], a2 = h4[2], a3 = h4[3];
    float hin[16] = {a0.x, a0.y, a0.z, a0.w, a1.x, a1.y, a1.z, a1.w,
                     a2.x, a2.y, a2.z, a2.w, a3.x, a3.y, a3.z, a3.w};
    float z0 = b3[0], z1 = b3[1];
    for (int o = 0; o < 32; o++) {
        float acc = b2[o];
        #pragma unroll
        for (int i = 0; i < 16; i++) acc += hin[i] * w2[i * 32 + o];
        acc = fmaxf(acc, 0.f);
        z0 += acc * w3[o * 2];
        z1 += acc * w3[o * 2 + 1];
    }
    out[g] = make_float2(z0, z1);
}

extern "C" void kernel_launch(void* const* d_in, const int* in_sizes, int n_in,
                              void* d_out, int out_size, void* d_ws, size_t ws_size,
                              hipStream_t stream) {
    (void)in_sizes; (void)n_in; (void)out_size; (void)ws_size;
    const float* x = (const float*)d_in[0];
    const int* edges = (const int*)d_in[1];
    Params12 wp;
    for (int i = 0; i < 12; i++) wp.p[i] = (const float*)d_in[2 + i];
    const float* fc1w = (const float*)d_in[14];
    const float* fc1b = (const float*)d_in[15];
    const float* bn1g = (const float*)d_in[16];
    const float* bn1b = (const float*)d_in[17];
    const float* fc2w = (const float*)d_in[18];
    const float* fc2b = (const float*)d_in[19];
    const float* bn2g = (const float*)d_in[20];
    const float* bn2b = (const float*)d_in[21];
    const float* fc3w = (const float*)d_in[22];
    const float* fc3b = (const float*)d_in[23];

    float* ws = (float*)d_ws;
    float* h1 = ws + WS_H1;

    k0_pre<<<1, 256, 0, stream>>>(wp, fc1w, fc1b, ws);
    k1_gcn<<<NGRAPH / GPB, 256, 0, stream>>>(x, edges, ws, h1);
    k23_stats_fold<<<256, 256, 0, stream>>>(h1, fc2w, fc2b, bn1g, bn1b, ws);
    k45_fc2_fold<<<NGRAPH / 256, 256, 0, stream>>>(h1, fc3w, fc3b, bn2g, bn2b, ws);
    k6_out<<<NGRAPH / 256, 256, 0, stream>>>(h1, ws, (float2*)d_out);
}